// Round 4
// baseline (395.580 us; speedup 1.0000x reference)
//
#include <hip/hip_runtime.h>
#include <hip/hip_fp16.h>

// TemporalKplanesEncoding: out[p, :] = sum_{k=0..2} bilinear(plane_k, inp[p,k], inp[p,3])
// planes: [F=32, H=128, W=256] f32.  N = 2097152 points.
//
// R5 strategy (R6 = compile fix): rocprof shows no dispatch of ours exceeds
// ~186 us, yet dur=386: the ~190 us 1 GiB workspace re-poison fill is inside
// the timed window. So: use NO workspace. The global binning pass is replaced
// by a per-block LDS counting sort (8192 pts -> 128 KB LDS), and gathers go to
// a 6 MB fp16 transposed texture [k][y][x][32f] in global memory. All 256
// blocks sweep t-rows in ascending order roughly in phase, so the per-XCD L2
// working set is a narrow row band -> L2-hit gathers. Out lines (128 B
// full-line per point) are written nontemporally so the dead 256 MB write
// stream doesn't thrash L2.
//
// R6 fix: __builtin_nontemporal_load/store reject HIP_vector_type<float,4>;
// use clang ext_vector_type(4) float (bit-identical) for those accesses.

#define NPTS 2097152
#define FEAT 32
#define PW 256
#define PH 128
#define NBINS 128
#define PPB 8192                       // points per block (NPTS / 256)

typedef float fx4 __attribute__((ext_vector_type(4)));

// fp16 texture, texel = 32 feats = 4 uint4; index ((k*PH + y)*PW + x)*4 + f4
__device__ uint4 g_tex[3 * PH * PW * 4];   // 6 MB

__device__ __forceinline__ unsigned int pk16(float a, float b) {
    __half2 h = __floats2half2_rn(a, b);
    return *reinterpret_cast<unsigned int*>(&h);
}
__device__ __forceinline__ float2 up16(unsigned int u) {
    __half2 h = *reinterpret_cast<__half2*>(&u);
    return __half22float2(h);
}

// 384 blocks = (k, y); LDS bounce for the [F][x] -> [x][F] transpose.
__global__ __launch_bounds__(256) void transpose_kernel(
    const float* __restrict__ p0,
    const float* __restrict__ p1,
    const float* __restrict__ p2) {
    __shared__ float b[FEAT][PW + 2];      // +2 pad: column reads 2-way max
    const int k = blockIdx.x >> 7;
    const int y = blockIdx.x & 127;
    const int tid = threadIdx.x;
    const float* src = ((k == 0) ? p0 : (k == 1) ? p1 : p2) + y * PW;
#pragma unroll
    for (int f = 0; f < FEAT; ++f)          // 1 KB coalesced per iter
        b[f][tid] = src[(size_t)f * (PH * PW) + tid];
    __syncthreads();
    const int x = tid;                      // one texel per thread, 64 B write
    uint4 v[4];
#pragma unroll
    for (int j = 0; j < 4; ++j) {
        v[j].x = pk16(b[8 * j + 0][x], b[8 * j + 1][x]);
        v[j].y = pk16(b[8 * j + 2][x], b[8 * j + 3][x]);
        v[j].z = pk16(b[8 * j + 4][x], b[8 * j + 5][x]);
        v[j].w = pk16(b[8 * j + 6][x], b[8 * j + 7][x]);
    }
    uint4* dst = g_tex + (size_t)(((k * PH + y) * PW + x)) * 4;
#pragma unroll
    for (int j = 0; j < 4; ++j) dst[j] = v[j];
}

// 256 blocks x 1024 threads x 8 points. Phase 1: LDS counting sort by t-row.
// Phase 2: 4 feature-lanes per point, ascending-row gathers from g_tex (L2),
// full-line nontemporal out writes.
__global__ __launch_bounds__(1024) void sample_kernel(
    const float* __restrict__ inp,
    float* __restrict__ out) {
    __shared__ float4 spts[PPB];           // 128 KB sorted payloads
    __shared__ int hist[NBINS];
    __shared__ int sA[NBINS], sB[NBINS];

    const int tid = threadIdx.x;
    const size_t pbase = (size_t)blockIdx.x * PPB;

    if (tid < NBINS) hist[tid] = 0;
    __syncthreads();

    // --- phase 1a: load 8 pts/thread, bin, grab in-bin position ---
    float4 c[8];
    int tag[8];                            // (bin<<16) | lpos
    unsigned int pw[8];                    // (bin<<24) | (lid<<11) | wy_q11
#pragma unroll
    for (int i = 0; i < 8; ++i) {
        int lid = tid + i * 1024;
        fx4 cv = __builtin_nontemporal_load(
            reinterpret_cast<const fx4*>(inp) + (pbase + lid));
        c[i] = make_float4(cv.x, cv.y, cv.z, cv.w);
        float y = fminf(fmaxf((c[i].w + 1.0f) * 63.5f, 0.0f), 127.0f);
        float bf = floorf(y);
        int bin = (int)bf;                           // 0..127
        int wyq = (int)((y - bf) * 2048.0f);         // 11-bit wy
        pw[i] = ((unsigned int)bin << 24) | ((unsigned int)lid << 11)
              | (unsigned int)wyq;
        int lpos = atomicAdd(&hist[bin], 1);         // <= 8191
        tag[i] = (bin << 16) | lpos;
    }
    __syncthreads();

    // --- phase 1b: Hillis-Steele inclusive scan of hist (7 steps) ---
    if (tid < NBINS) sA[tid] = hist[tid];
    __syncthreads();
#pragma unroll
    for (int step = 1, s = 0; step < NBINS; step <<= 1, ++s) {
        if (tid < NBINS) {
            const int* rd = (s & 1) ? sB : sA;
            int* wr = (s & 1) ? sA : sB;
            int v = rd[tid];
            if (tid >= step) v += rd[tid - step];
            wr[tid] = v;
        }
        __syncthreads();
    }
    // 7 steps -> inclusive result in sB; exclusive start -> sA
    if (tid < NBINS) sA[tid] = sB[tid] - hist[tid];
    __syncthreads();

    // --- phase 1c: scatter into sorted LDS order ---
#pragma unroll
    for (int i = 0; i < 8; ++i) {
        int pos = sA[tag[i] >> 16] + (tag[i] & 0xffff);
        spts[pos] = make_float4(c[i].x, c[i].y, c[i].z, __uint_as_float(pw[i]));
    }
    __syncthreads();

    // --- phase 2: sorted sweep, 4 lanes/point ---
    const int f4 = tid & 3;                // feature group: feats f4*8..f4*8+7
    const uint4* tex = g_tex;

    for (int it = 0; it < PPB / 256; ++it) {   // 32 iters
        float4 p = spts[it * 256 + (tid >> 2)]; // 4 lanes broadcast 16 B
        unsigned int w = __float_as_uint(p.w);
        int bin = (int)(w >> 24);
        int lid = (int)((w >> 11) & 8191u);
        float wy = (float)(w & 2047u) * (1.0f / 2048.0f);
        float omy = 1.0f - wy;
        int y1 = min(bin + 1, PH - 1);

        float a0 = 0, a1 = 0, a2 = 0, a3 = 0, a4 = 0, a5 = 0, a6 = 0, a7 = 0;
        const float cx[3] = {p.x, p.y, p.z};
#pragma unroll
        for (int k = 0; k < 3; ++k) {
            float x = fminf(fmaxf((cx[k] + 1.0f) * 127.5f, 0.0f), 255.0f);
            float x0f = floorf(x);
            float wx = x - x0f;
            float omx = 1.0f - wx;
            int x0 = (int)x0f;
            int x1 = min(x0 + 1, PW - 1);
            float w00 = omx * omy, w01 = wx * omy;
            float w10 = omx * wy, w11 = wx * wy;

            int rb0 = (k * PH + bin) * PW;
            int rb1 = (k * PH + y1) * PW;
            uint4 t00 = tex[((rb0 + x0) << 2) | f4];
            uint4 t01 = tex[((rb0 + x1) << 2) | f4];
            uint4 t10 = tex[((rb1 + x0) << 2) | f4];
            uint4 t11 = tex[((rb1 + x1) << 2) | f4];
#define ACC(T, W) { float2 u0 = up16(T.x), u1 = up16(T.y), u2 = up16(T.z), u3 = up16(T.w); \
            a0 += u0.x * W; a1 += u0.y * W; a2 += u1.x * W; a3 += u1.y * W; \
            a4 += u2.x * W; a5 += u2.y * W; a6 += u3.x * W; a7 += u3.y * W; }
            ACC(t00, w00) ACC(t01, w01) ACC(t10, w10) ACC(t11, w11)
#undef ACC
        }
        // full 128 B line: 4 lanes x 32 B, nontemporal (dead stream, skip L2)
        float* op = out + ((pbase + (size_t)lid) << 5) + (f4 << 3);
        fx4 o0 = {a0, a1, a2, a3};
        fx4 o1 = {a4, a5, a6, a7};
        __builtin_nontemporal_store(o0, reinterpret_cast<fx4*>(op));
        __builtin_nontemporal_store(o1, reinterpret_cast<fx4*>(op + 4));
    }
}

extern "C" void kernel_launch(void* const* d_in, const int* in_sizes, int n_in,
                              void* d_out, int out_size, void* d_ws, size_t ws_size,
                              hipStream_t stream) {
    const float* inp = (const float*)d_in[0];
    const float* pl0 = (const float*)d_in[1];
    const float* pl1 = (const float*)d_in[2];
    const float* pl2 = (const float*)d_in[3];
    float* out = (float*)d_out;
    (void)d_ws; (void)ws_size;   // no workspace: avoids the timed re-poison fill

    transpose_kernel<<<3 * PH, 256, 0, stream>>>(pl0, pl1, pl2);
    sample_kernel<<<NPTS / PPB, 1024, 0, stream>>>(inp, out);
}

// Round 5
// 388.517 us; speedup vs baseline: 1.0182x; 1.0182x over previous
//
#include <hip/hip_runtime.h>
#include <hip/hip_fp16.h>

// TemporalKplanesEncoding: out[p, :] = sum_{k=0..2} bilinear(plane_k, inp[p,k], inp[p,3])
// planes: [F=32, H=128, W=256] f32.  N = 2097152 points.
//
// R7 strategy: R6's sample_kernel was latency-bound (Occupancy 34%, HBM 28%,
// VALU 33%): 129.5 KB LDS forced 1 block/CU = 16 waves. R7 halves the
// per-block point count (PPB 4096, 512 blocks): 65.5 KB LDS -> 2 blocks/CU
// = 32 waves/CU (hardware cap), doubling latency hiding for the dependent
// gather chain. Fused design otherwise unchanged: per-block LDS counting sort
// by t-row, gathers from a 6 MB fp16 transposed texture [k][y][x][32f]
// (L2-resident row band), full-line 128 B nontemporal out writes.

#define NPTS 2097152
#define FEAT 32
#define PW 256
#define PH 128
#define NBINS 128
#define PPB 4096                       // points per block (NPTS / 512)
#define PPT (PPB / 1024)               // 4 points per thread

typedef float fx4 __attribute__((ext_vector_type(4)));

// fp16 texture, texel = 32 feats = 4 uint4; index ((k*PH + y)*PW + x)*4 + f4
__device__ uint4 g_tex[3 * PH * PW * 4];   // 6 MB

__device__ __forceinline__ unsigned int pk16(float a, float b) {
    __half2 h = __floats2half2_rn(a, b);
    return *reinterpret_cast<unsigned int*>(&h);
}
__device__ __forceinline__ float2 up16(unsigned int u) {
    __half2 h = *reinterpret_cast<__half2*>(&u);
    return __half22float2(h);
}

// 384 blocks = (k, y); LDS bounce for the [F][x] -> [x][F] transpose.
__global__ __launch_bounds__(256) void transpose_kernel(
    const float* __restrict__ p0,
    const float* __restrict__ p1,
    const float* __restrict__ p2) {
    __shared__ float b[FEAT][PW + 2];      // +2 pad: column reads 2-way max
    const int k = blockIdx.x >> 7;
    const int y = blockIdx.x & 127;
    const int tid = threadIdx.x;
    const float* src = ((k == 0) ? p0 : (k == 1) ? p1 : p2) + y * PW;
#pragma unroll
    for (int f = 0; f < FEAT; ++f)          // 1 KB coalesced per iter
        b[f][tid] = src[(size_t)f * (PH * PW) + tid];
    __syncthreads();
    const int x = tid;                      // one texel per thread, 64 B write
    uint4 v[4];
#pragma unroll
    for (int j = 0; j < 4; ++j) {
        v[j].x = pk16(b[8 * j + 0][x], b[8 * j + 1][x]);
        v[j].y = pk16(b[8 * j + 2][x], b[8 * j + 3][x]);
        v[j].z = pk16(b[8 * j + 4][x], b[8 * j + 5][x]);
        v[j].w = pk16(b[8 * j + 6][x], b[8 * j + 7][x]);
    }
    uint4* dst = g_tex + (size_t)(((k * PH + y) * PW + x)) * 4;
#pragma unroll
    for (int j = 0; j < 4; ++j) dst[j] = v[j];
}

// 512 blocks x 1024 threads x 4 points. Phase 1: LDS counting sort by t-row.
// Phase 2: 4 feature-lanes per point, ascending-row gathers from g_tex (L2),
// full-line nontemporal out writes.
__global__ __launch_bounds__(1024) void sample_kernel(
    const float* __restrict__ inp,
    float* __restrict__ out) {
    __shared__ float4 spts[PPB];           // 64 KB sorted payloads
    __shared__ int hist[NBINS];
    __shared__ int sA[NBINS], sB[NBINS];

    const int tid = threadIdx.x;
    const size_t pbase = (size_t)blockIdx.x * PPB;

    if (tid < NBINS) hist[tid] = 0;
    __syncthreads();

    // --- phase 1a: load 4 pts/thread, bin, grab in-bin position ---
    float4 c[PPT];
    int tag[PPT];                          // (bin<<16) | lpos
    unsigned int pw[PPT];                  // (bin<<24) | (lid<<11) | wy_q11
#pragma unroll
    for (int i = 0; i < PPT; ++i) {
        int lid = tid + i * 1024;
        fx4 cv = __builtin_nontemporal_load(
            reinterpret_cast<const fx4*>(inp) + (pbase + lid));
        c[i] = make_float4(cv.x, cv.y, cv.z, cv.w);
        float y = fminf(fmaxf((c[i].w + 1.0f) * 63.5f, 0.0f), 127.0f);
        float bf = floorf(y);
        int bin = (int)bf;                           // 0..127
        int wyq = (int)((y - bf) * 2048.0f);         // 11-bit wy
        pw[i] = ((unsigned int)bin << 24) | ((unsigned int)lid << 11)
              | (unsigned int)wyq;
        int lpos = atomicAdd(&hist[bin], 1);         // <= PPB-1
        tag[i] = (bin << 16) | lpos;
    }
    __syncthreads();

    // --- phase 1b: Hillis-Steele inclusive scan of hist (7 steps) ---
    if (tid < NBINS) sA[tid] = hist[tid];
    __syncthreads();
#pragma unroll
    for (int step = 1, s = 0; step < NBINS; step <<= 1, ++s) {
        if (tid < NBINS) {
            const int* rd = (s & 1) ? sB : sA;
            int* wr = (s & 1) ? sA : sB;
            int v = rd[tid];
            if (tid >= step) v += rd[tid - step];
            wr[tid] = v;
        }
        __syncthreads();
    }
    // 7 steps -> inclusive result in sB; exclusive start -> sA
    if (tid < NBINS) sA[tid] = sB[tid] - hist[tid];
    __syncthreads();

    // --- phase 1c: scatter into sorted LDS order ---
#pragma unroll
    for (int i = 0; i < PPT; ++i) {
        int pos = sA[tag[i] >> 16] + (tag[i] & 0xffff);
        spts[pos] = make_float4(c[i].x, c[i].y, c[i].z, __uint_as_float(pw[i]));
    }
    __syncthreads();

    // --- phase 2: sorted sweep, 4 lanes/point ---
    const int f4 = tid & 3;                // feature group: feats f4*8..f4*8+7
    const uint4* tex = g_tex;

    for (int it = 0; it < PPB / 256; ++it) {   // 16 iters
        float4 p = spts[it * 256 + (tid >> 2)]; // 4 lanes broadcast 16 B
        unsigned int w = __float_as_uint(p.w);
        int bin = (int)(w >> 24);
        int lid = (int)((w >> 11) & 8191u);
        float wy = (float)(w & 2047u) * (1.0f / 2048.0f);
        float omy = 1.0f - wy;
        int y1 = min(bin + 1, PH - 1);

        float a0 = 0, a1 = 0, a2 = 0, a3 = 0, a4 = 0, a5 = 0, a6 = 0, a7 = 0;
        const float cx[3] = {p.x, p.y, p.z};
#pragma unroll
        for (int k = 0; k < 3; ++k) {
            float x = fminf(fmaxf((cx[k] + 1.0f) * 127.5f, 0.0f), 255.0f);
            float x0f = floorf(x);
            float wx = x - x0f;
            float omx = 1.0f - wx;
            int x0 = (int)x0f;
            int x1 = min(x0 + 1, PW - 1);
            float w00 = omx * omy, w01 = wx * omy;
            float w10 = omx * wy, w11 = wx * wy;

            int rb0 = (k * PH + bin) * PW;
            int rb1 = (k * PH + y1) * PW;
            uint4 t00 = tex[((rb0 + x0) << 2) | f4];
            uint4 t01 = tex[((rb0 + x1) << 2) | f4];
            uint4 t10 = tex[((rb1 + x0) << 2) | f4];
            uint4 t11 = tex[((rb1 + x1) << 2) | f4];
#define ACC(T, W) { float2 u0 = up16(T.x), u1 = up16(T.y), u2 = up16(T.z), u3 = up16(T.w); \
            a0 += u0.x * W; a1 += u0.y * W; a2 += u1.x * W; a3 += u1.y * W; \
            a4 += u2.x * W; a5 += u2.y * W; a6 += u3.x * W; a7 += u3.y * W; }
            ACC(t00, w00) ACC(t01, w01) ACC(t10, w10) ACC(t11, w11)
#undef ACC
        }
        // full 128 B line: 4 lanes x 32 B, nontemporal (dead stream, skip L2)
        float* op = out + ((pbase + (size_t)lid) << 5) + (f4 << 3);
        fx4 o0 = {a0, a1, a2, a3};
        fx4 o1 = {a4, a5, a6, a7};
        __builtin_nontemporal_store(o0, reinterpret_cast<fx4*>(op));
        __builtin_nontemporal_store(o1, reinterpret_cast<fx4*>(op + 4));
    }
}

extern "C" void kernel_launch(void* const* d_in, const int* in_sizes, int n_in,
                              void* d_out, int out_size, void* d_ws, size_t ws_size,
                              hipStream_t stream) {
    const float* inp = (const float*)d_in[0];
    const float* pl0 = (const float*)d_in[1];
    const float* pl1 = (const float*)d_in[2];
    const float* pl2 = (const float*)d_in[3];
    float* out = (float*)d_out;
    (void)d_ws; (void)ws_size;   // no workspace used

    transpose_kernel<<<3 * PH, 256, 0, stream>>>(pl0, pl1, pl2);
    sample_kernel<<<NPTS / PPB, 1024, 0, stream>>>(inp, out);
}